// Round 5
// baseline (709.950 us; speedup 1.0000x reference)
//
#include <hip/hip_runtime.h>
#include <hip/hip_bf16.h>

#define N_NODES 50000
#define N_EDGES 1000000
#define C       128
#define N_REL   8
#define N_SEG   (N_NODES * N_REL)       // 400000
#define KTOT    (N_REL * C + C)         // 1152 = 8 rel chunks + self
#define KC_CNT  (KTOT / 32)             // 36 MFMA k-chunks
#define A_STRIDE 1160                   // 1152 + 8 bf16 pad per row

typedef __hip_bfloat16  bf16;
typedef __hip_bfloat162 bf162;
typedef __attribute__((ext_vector_type(8))) short short8;
typedef __attribute__((ext_vector_type(4))) float f32x4;

// ---------------------------------------------------------------- CSR build
__global__ void count_kernel(const int* __restrict__ dst, const int* __restrict__ et,
                             int* __restrict__ cnt) {
    int e = blockIdx.x * blockDim.x + threadIdx.x;
    if (e < N_EDGES) atomicAdd(&cnt[dst[e] * N_REL + et[e]], 1);
}

// exclusive scan, level 1: 1024 elements / block (256 thr x 4)
__global__ void scan1_kernel(const int* __restrict__ cnt, int* __restrict__ offs,
                             int* __restrict__ partials, int n) {
    __shared__ int tot[256];
    int t = threadIdx.x;
    int base = blockIdx.x * 1024 + t * 4;
    int v0 = (base + 0 < n) ? cnt[base + 0] : 0;
    int v1 = (base + 1 < n) ? cnt[base + 1] : 0;
    int v2 = (base + 2 < n) ? cnt[base + 2] : 0;
    int v3 = (base + 3 < n) ? cnt[base + 3] : 0;
    int tsum = v0 + v1 + v2 + v3;
    tot[t] = tsum;
    __syncthreads();
    for (int d = 1; d < 256; d <<= 1) {
        int x = tot[t];
        int y = (t >= d) ? tot[t - d] : 0;
        __syncthreads();
        tot[t] = x + y;
        __syncthreads();
    }
    int excl = tot[t] - tsum;
    if (base + 0 < n) offs[base + 0] = excl;
    if (base + 1 < n) offs[base + 1] = excl + v0;
    if (base + 2 < n) offs[base + 2] = excl + v0 + v1;
    if (base + 3 < n) offs[base + 3] = excl + v0 + v1 + v2;
    if (t == 255) partials[blockIdx.x] = tot[255];
}

// level 2: single-block exclusive scan of block partials (nb <= 512)
__global__ void scan2_kernel(const int* __restrict__ partials, int* __restrict__ pofs, int nb) {
    __shared__ int s[512];
    int t = threadIdx.x;
    int orig = (t < nb) ? partials[t] : 0;
    s[t] = orig;
    __syncthreads();
    for (int d = 1; d < 512; d <<= 1) {
        int x = s[t];
        int y = (t >= d) ? s[t - d] : 0;
        __syncthreads();
        s[t] = x + y;
        __syncthreads();
    }
    if (t < nb) pofs[t] = s[t] - orig;
}

// level 3: add block offsets; init the fill cursor; write sentinel
__global__ void scan3_kernel(int* __restrict__ offs, const int* __restrict__ pofs,
                             int* __restrict__ cur, int n, int total) {
    int add = pofs[blockIdx.x];
    int base = blockIdx.x * 1024 + threadIdx.x * 4;
#pragma unroll
    for (int j = 0; j < 4; j++)
        if (base + j < n) {
            int v = offs[base + j] + add;
            offs[base + j] = v;
            cur[base + j]  = v;
        }
    if (blockIdx.x == 0 && threadIdx.x == 0) offs[n] = total;
}

__global__ void fill_kernel(const int* __restrict__ src, const int* __restrict__ dst,
                            const int* __restrict__ et, int* __restrict__ cur,
                            int* __restrict__ srcs) {
    int e = blockIdx.x * blockDim.x + threadIdx.x;
    if (e < N_EDGES) {
        int seg = dst[e] * N_REL + et[e];
        int pos = atomicAdd(&cur[seg], 1);
        srcs[pos] = src[e];
    }
}

// move CSR (offs + srcs) from d_out scratch into the dead ei buffer
__global__ void move_kernel(const int* __restrict__ offs, const int* __restrict__ srcs,
                            int* __restrict__ offs2, int* __restrict__ srcs2) {
    int i = blockIdx.x * blockDim.x + threadIdx.x;
    if (i < N_SEG + 1)                offs2[i] = offs[i];
    else if (i < N_SEG + 1 + N_EDGES) srcs2[i - (N_SEG + 1)] = srcs[i - (N_SEG + 1)];
}

// ---------------------------------------------------------------- weight repack
// B-fragment for mfma_f32_16x16x32_bf16: lane = quad*16 + (n&15) holds
// B[k = kc*32 + quad*8 + j][n], j=0..7 contiguous.
__device__ __forceinline__ size_t frag_index(int k, int n) {
    int nt = n >> 4, n15 = n & 15;
    int kc = k >> 5, quad = (k >> 3) & 3, j = k & 7;
    int lane = quad * 16 + n15;
    return ((size_t)(nt * KC_CNT + kc) * 64 + lane) * 8 + j;
}

// Wcat1 = [W1 ; root1] (fp32 in) -> bf16 fragments
__global__ void repack1_kernel(const float* __restrict__ W, const float* __restrict__ root,
                               bf16* __restrict__ Bp) {
    int idx = blockIdx.x * blockDim.x + threadIdx.x;
    if (idx >= KTOT * C) return;
    int k = idx >> 7, n = idx & 127;
    float val;
    if (k < N_REL * C) val = W[(size_t)k * C + n];
    else               val = root[(size_t)(k - N_REL * C) * C + n];
    Bp[frag_index(k, n)] = __float2bfloat16(val);
}

// C2[k][n] = sum_m Wcat2[k][m] * linW[m][n]  (fp32 in/acc) -> bf16 fragments
__global__ void repack2_kernel(const float* __restrict__ W, const float* __restrict__ root,
                               const float* __restrict__ linW, bf16* __restrict__ Bp) {
    int idx = blockIdx.x * blockDim.x + threadIdx.x;
    if (idx >= KTOT * C) return;
    int k = idx >> 7, n = idx & 127;
    const float* row = (k < N_REL * C) ? (W + (size_t)k * C)
                                       : (root + (size_t)(k - N_REL * C) * C);
    float acc = 0.f;
    for (int m = 0; m < C; m++)
        acc += row[m] * linW[(size_t)m * C + n];
    Bp[frag_index(k, n)] = __float2bfloat16(acc);
}

__global__ void bias2_kernel(const float* __restrict__ b2, const float* __restrict__ linW,
                             const float* __restrict__ linb, float* __restrict__ b2p) {
    int n = threadIdx.x;   // 128 threads
    float acc = linb[n];
    for (int m = 0; m < C; m++)
        acc += b2[m] * linW[(size_t)m * C + n];
    b2p[n] = acc;
}

// ---------------------------------------------------------------- fused layer
// Block: 16 nodes, 256 threads (4 waves).
// Phase 1: CSR gather (fp32 or bf16 features) -> fp32 mean -> bf16 A-tile in LDS.
// Phase 2: MFMA [16 x KTOT] x [KTOT x 128], 2 N-tiles per wave.
// FEAT_F32: input features fp32 (layer 1) vs bf16 (layer 2).
// OUT_F32:  output fp32 (layer 2) vs bf16 (layer 1 intermediate).
template <int RELU, int FEAT_F32, int OUT_F32>
__global__ __launch_bounds__(256, 4) void fused_layer(
        const void*  __restrict__ feat,      // [N][128] fp32 or bf16
        const int*   __restrict__ offs,      // [N_SEG+1]
        const int*   __restrict__ srcs,      // [N_EDGES]
        const short8* __restrict__ Bp,       // fragment-packed bf16 weights
        const float* __restrict__ bias,      // [128] fp32
        void* __restrict__ outp)             // [N][128] fp32 or bf16
{
    __shared__ __align__(16) unsigned int At[16 * (A_STRIDE / 2)];  // bf16 pairs
    const int tid  = threadIdx.x;
    const int lane = tid & 63;
    const int w    = tid >> 6;
    const int v0   = blockIdx.x * 16;

    // zero the 4 pad pairs per row (never read by the MFMA loop, but cheap)
    if (tid < 16 * 4) At[(tid >> 2) * (A_STRIDE / 2) + 576 + (tid & 3)] = 0u;

    // self rows -> k range [1024..1151]
    for (int q = tid; q < 16 * 64; q += 256) {
        int node = q >> 6, p = q & 63;
        unsigned int u;
        if (FEAT_F32) {
            float2 v = ((const float2*)feat)[(size_t)(v0 + node) * 64 + p];
            union { bf162 h; unsigned int uu; } cv;
            cv.h = bf162(__float2bfloat16(v.x), __float2bfloat16(v.y));
            u = cv.uu;
        } else {
            u = ((const unsigned int*)feat)[(size_t)(v0 + node) * 64 + p];
        }
        At[node * (A_STRIDE / 2) + 512 + p] = u;
    }

    // per-(node, rel) mean aggregation; one wave per segment, 2 channels/lane
    for (int si = w; si < 16 * N_REL; si += 4) {
        int node = si >> 3, rel = si & 7;
        int seg  = (v0 + node) * N_REL + rel;
        int beg  = offs[seg], end = offs[seg + 1];
        float a0 = 0.f, a1 = 0.f;
        for (int i = beg; i < end; i++) {
            int sv = srcs[i];
            if (FEAT_F32) {
                float2 v = ((const float2*)feat)[(size_t)sv * 64 + lane];
                a0 += v.x; a1 += v.y;
            } else {
                bf162 h = ((const bf162*)feat)[(size_t)sv * 64 + lane];
                a0 += __low2float(h); a1 += __high2float(h);
            }
        }
        float inv = (end > beg) ? 1.0f / (float)(end - beg) : 0.0f;
        a0 *= inv; a1 *= inv;
        union { bf162 h; unsigned int u; } cv;
        cv.h = bf162(__float2bfloat16(a0), __float2bfloat16(a1));
        At[node * (A_STRIDE / 2) + rel * 64 + lane] = cv.u;
    }
    __syncthreads();

    // MFMA GEMM
    const int quad = lane >> 4, n15 = lane & 15;
    const int nt0 = 2 * w, nt1 = 2 * w + 1;
    f32x4 acc0 = {0.f, 0.f, 0.f, 0.f};
    f32x4 acc1 = {0.f, 0.f, 0.f, 0.f};
    const short* Ash = (const short*)At;

    for (int kc = 0; kc < KC_CNT; kc++) {
        short8 a  = *reinterpret_cast<const short8*>(Ash + n15 * A_STRIDE + kc * 32 + quad * 8);
        short8 b0 = Bp[(size_t)(nt0 * KC_CNT + kc) * 64 + lane];
        short8 b1 = Bp[(size_t)(nt1 * KC_CNT + kc) * 64 + lane];
        acc0 = __builtin_amdgcn_mfma_f32_16x16x32_bf16(a, b0, acc0, 0, 0, 0);
        acc1 = __builtin_amdgcn_mfma_f32_16x16x32_bf16(a, b1, acc1, 0, 0, 0);
    }

    // epilogue: D[m = quad*4 + r][n = nt*16 + n15]
#pragma unroll
    for (int t = 0; t < 2; t++) {
        int nt = t ? nt1 : nt0;
        f32x4 acc = t ? acc1 : acc0;
        int col = nt * 16 + n15;
        float bv = bias[col];
#pragma unroll
        for (int r = 0; r < 4; r++) {
            int m = quad * 4 + r;
            float v = acc[r] + bv;
            if (RELU) v = fmaxf(v, 0.f);
            if (OUT_F32) ((float*)outp)[(size_t)(v0 + m) * C + col] = v;
            else         ((bf16*)outp)[(size_t)(v0 + m) * C + col] = __float2bfloat16(v);
        }
    }
}

// ---------------------------------------------------------------- 16B copy
typedef struct { unsigned int a, b, c, d; } u128;
__global__ void copy16_kernel(const u128* __restrict__ in, u128* __restrict__ out, int n) {
    int i = blockIdx.x * blockDim.x + threadIdx.x;
    if (i < n) out[i] = in[i];
}

// ---------------------------------------------------------------- launch
// fp32 I/O world. ZERO d_ws usage. Scratch provenance:
//   CSR build scratch     -> d_out (25.6 MB fp32 output buffer, free until h1)
//   final CSR (offs+srcs) -> ei's buffer (8 MB, dead after fill)
//   packed weights        -> et's buffer (4 MB, dead after fill)
//   h1 (bf16, 12.8 MB)    -> d_out[0..12.8MB]
//   layer-2 fp32 out      -> x's buffer (25.6 MB, dead after layer 1)
//   final copy            -> d_out (full 25.6 MB)
extern "C" void kernel_launch(void* const* d_in, const int* in_sizes, int n_in,
                              void* d_out, int out_size, void* d_ws, size_t ws_size,
                              hipStream_t stream) {
    const float* x     = (const float*)d_in[0];
    const int*   ei    = (const int*)d_in[1];
    const int*   et    = (const int*)d_in[2];
    const float* W1    = (const float*)d_in[3];
    const float* root1 = (const float*)d_in[4];
    const float* b1    = (const float*)d_in[5];
    const float* W2    = (const float*)d_in[6];
    const float* root2 = (const float*)d_in[7];
    const float* b2    = (const float*)d_in[8];
    const float* linW  = (const float*)d_in[9];
    const float* linb  = (const float*)d_in[10];
    float* out = (float*)d_out;

    const int* src = ei;
    const int* dst = ei + N_EDGES;

    // ---- CSR scratch inside d_out (used only BEFORE layer 1 writes h1)
    char* ob = (char*)d_out;
    int* cnt_i    = (int*)(ob + 0);          // 1,600,000 B (reused as fill cursor)
    int* offs_t   = (int*)(ob + 1600256);    // 1,600,004 B
    int* partials = (int*)(ob + 3200512);    // 1,564 B
    int* pofs     = (int*)(ob + 3202176);    // 1,564 B
    int* srcs_t   = (int*)(ob + 3204096);    // 4,000,000 B -> ends 7,204,096 < 25.6 MB

    // ---- final CSR home: ei's buffer (8 MB, dead after fill_kernel)
    char* eb = (char*)d_in[1];
    int* offs2 = (int*)(eb + 0);             // 1,600,004 B
    int* srcs2 = (int*)(eb + 1600256);       // 4,000,000 B -> ends 5,600,256 < 8 MB

    // ---- packed weights: et's buffer (4 MB, dead after fill_kernel)
    char* tb = (char*)d_in[2];
    bf16*  Bp1 = (bf16*)(tb + 0);            // 294,912 B
    bf16*  Bp2 = (bf16*)(tb + 295168);       // 294,912 B
    float* b2p = (float*)(tb + 590336);      // 512 B -> ends < 4 MB

    bf16*  h1  = (bf16*)d_out;               // layer-1 bf16 out -> d_out[0..12.8MB]
    float* fin = (float*)d_in[0];            // layer-2 fp32 out -> x's buffer

    const int nscan1 = (N_SEG + 1023) / 1024;   // 391 blocks

    // ---- CSR build (scratch in d_out; ei/et still live as inputs here)
    hipMemsetAsync(cnt_i, 0, (size_t)N_SEG * 4, stream);
    count_kernel<<<(N_EDGES + 255) / 256, 256, 0, stream>>>(dst, et, cnt_i);
    scan1_kernel<<<nscan1, 256, 0, stream>>>(cnt_i, offs_t, partials, N_SEG);
    scan2_kernel<<<1, 512, 0, stream>>>(partials, pofs, nscan1);
    scan3_kernel<<<nscan1, 256, 0, stream>>>(offs_t, pofs, cnt_i, N_SEG, N_EDGES);
    fill_kernel<<<(N_EDGES + 255) / 256, 256, 0, stream>>>(src, dst, et, cnt_i, srcs_t);

    // ---- relocate CSR into ei's buffer (ei dead now)
    {
        int n = N_SEG + 1 + N_EDGES;
        move_kernel<<<(n + 255) / 256, 256, 0, stream>>>(offs_t, srcs_t, offs2, srcs2);
    }

    // ---- weight prep into et's buffer (et dead now)
    const int nrep = (KTOT * C + 255) / 256;
    repack1_kernel<<<nrep, 256, 0, stream>>>(W1, root1, Bp1);
    repack2_kernel<<<nrep, 256, 0, stream>>>(W2, root2, linW, Bp2);
    bias2_kernel<<<1, 128, 0, stream>>>(b2, linW, linb, b2p);

    // ---- fused layers
    fused_layer<1, 1, 0><<<N_NODES / 16, 256, 0, stream>>>(
        (const void*)x, offs2, srcs2, (const short8*)Bp1, b1, (void*)h1);
    fused_layer<0, 0, 1><<<N_NODES / 16, 256, 0, stream>>>(
        (const void*)h1, offs2, srcs2, (const short8*)Bp2, b2p, (void*)fin);

    // ---- move result into d_out (16B chunks; 25.6 MB)
    {
        int n16 = (N_NODES * C * 4) / 16;   // 1,600,000
        copy16_kernel<<<(n16 + 255) / 256, 256, 0, stream>>>(
            (const u128*)fin, (u128*)out, n16);
    }

    (void)in_sizes; (void)n_in; (void)out_size; (void)d_ws; (void)ws_size;
}

// Round 6
// 568.193 us; speedup vs baseline: 1.2495x; 1.2495x over previous
//
#include <hip/hip_runtime.h>
#include <hip/hip_bf16.h>

#define N_NODES 50000
#define N_EDGES 1000000
#define C       128
#define N_REL   8
#define N_SEG   (N_NODES * N_REL)       // 400000
#define KTOT    (N_REL * C + C)         // 1152 = 8 rel chunks + self
#define KC_CNT  (KTOT / 32)             // 36 MFMA k-chunks
#define A_STRIDE 1160                   // 1152 + 8 bf16 pad per row

typedef __hip_bfloat16  bf16;
typedef __hip_bfloat162 bf162;
typedef __attribute__((ext_vector_type(8))) short short8;
typedef __attribute__((ext_vector_type(4))) float f32x4;

// ---------------------------------------------------------------- prep: x->bf16 cvt + seg count
#define CVT_BLOCKS ((N_NODES * C / 2) / 256)          // 12500 (exact)
#define CNT_BLOCKS ((N_EDGES + 255) / 256)            // 3907
__global__ void prep_kernel(const float2* __restrict__ xf, unsigned int* __restrict__ xb,
                            const int* __restrict__ dst, const int* __restrict__ et,
                            int* __restrict__ cnt) {
    int bid = blockIdx.x;
    if (bid < CVT_BLOCKS) {
        int i = bid * 256 + threadIdx.x;              // over N*C/2 float2, exact fit
        float2 v = xf[i];
        union { bf162 h; unsigned int u; } cv;
        cv.h = bf162(__float2bfloat16(v.x), __float2bfloat16(v.y));
        xb[i] = cv.u;
    } else {
        int e = (bid - CVT_BLOCKS) * 256 + threadIdx.x;
        if (e < N_EDGES) atomicAdd(&cnt[dst[e] * N_REL + et[e]], 1);
    }
}

// ---------------------------------------------------------------- scans
__global__ void scan1_kernel(const int* __restrict__ cnt, int* __restrict__ offs,
                             int* __restrict__ partials, int n) {
    __shared__ int tot[256];
    int t = threadIdx.x;
    int base = blockIdx.x * 1024 + t * 4;
    int v0 = (base + 0 < n) ? cnt[base + 0] : 0;
    int v1 = (base + 1 < n) ? cnt[base + 1] : 0;
    int v2 = (base + 2 < n) ? cnt[base + 2] : 0;
    int v3 = (base + 3 < n) ? cnt[base + 3] : 0;
    int tsum = v0 + v1 + v2 + v3;
    tot[t] = tsum;
    __syncthreads();
    for (int d = 1; d < 256; d <<= 1) {
        int x = tot[t];
        int y = (t >= d) ? tot[t - d] : 0;
        __syncthreads();
        tot[t] = x + y;
        __syncthreads();
    }
    int excl = tot[t] - tsum;
    if (base + 0 < n) offs[base + 0] = excl;
    if (base + 1 < n) offs[base + 1] = excl + v0;
    if (base + 2 < n) offs[base + 2] = excl + v0 + v1;
    if (base + 3 < n) offs[base + 3] = excl + v0 + v1 + v2;
    if (t == 255) partials[blockIdx.x] = tot[255];
}

__global__ void scan2_kernel(const int* __restrict__ partials, int* __restrict__ pofs, int nb) {
    __shared__ int s[512];
    int t = threadIdx.x;
    int orig = (t < nb) ? partials[t] : 0;
    s[t] = orig;
    __syncthreads();
    for (int d = 1; d < 512; d <<= 1) {
        int x = s[t];
        int y = (t >= d) ? s[t - d] : 0;
        __syncthreads();
        s[t] = x + y;
        __syncthreads();
    }
    if (t < nb) pofs[t] = s[t] - orig;
}

__global__ void scan3_kernel(int* __restrict__ offs, const int* __restrict__ pofs,
                             int* __restrict__ cur, int n, int total) {
    int add = pofs[blockIdx.x];
    int base = blockIdx.x * 1024 + threadIdx.x * 4;
#pragma unroll
    for (int j = 0; j < 4; j++)
        if (base + j < n) {
            int v = offs[base + j] + add;
            offs[base + j] = v;
            cur[base + j]  = v;
        }
    if (blockIdx.x == 0 && threadIdx.x == 0) offs[n] = total;
}

__global__ void fill_kernel(const int* __restrict__ src, const int* __restrict__ dst,
                            const int* __restrict__ et, int* __restrict__ cur,
                            int* __restrict__ srcs) {
    int e = blockIdx.x * blockDim.x + threadIdx.x;
    if (e < N_EDGES) {
        int seg = dst[e] * N_REL + et[e];
        int pos = atomicAdd(&cur[seg], 1);
        srcs[pos] = src[e];
    }
}

// ---------------------------------------------------------------- finalize: move CSR + repack weights
// B-fragment for mfma_f32_16x16x32_bf16: lane = quad*16 + (n&15) holds
// B[k = kc*32 + quad*8 + j][n], j=0..7 contiguous.
__device__ __forceinline__ size_t frag_index(int k, int n) {
    int nt = n >> 4, n15 = n & 15;
    int kc = k >> 5, quad = (k >> 3) & 3, j = k & 7;
    int lane = quad * 16 + n15;
    return ((size_t)(nt * KC_CNT + kc) * 64 + lane) * 8 + j;
}

#define MV_N (N_SEG + 1 + N_EDGES)        // 1,400,001
#define MV_B ((MV_N + 255) / 256)         // 5469
#define RP_B (KTOT * C / 256)             // 576 (exact)
__global__ void finalize_kernel(const int* __restrict__ offs_t, const int* __restrict__ srcs_t,
                                int* __restrict__ offs2, int* __restrict__ srcs2,
                                const float* __restrict__ W1, const float* __restrict__ root1,
                                const float* __restrict__ W2, const float* __restrict__ root2,
                                const float* __restrict__ linW,
                                const float* __restrict__ b2, const float* __restrict__ linb,
                                bf16* __restrict__ Bp1, bf16* __restrict__ Bp2,
                                float* __restrict__ b2p) {
    int bid = blockIdx.x;
    if (bid < MV_B) {
        int i = bid * 256 + threadIdx.x;
        if (i < N_SEG + 1)     offs2[i] = offs_t[i];
        else if (i < MV_N)     srcs2[i - (N_SEG + 1)] = srcs_t[i - (N_SEG + 1)];
    } else if (bid < MV_B + RP_B) {
        int idx = (bid - MV_B) * 256 + threadIdx.x;
        int k = idx >> 7, n = idx & 127;
        float val;
        if (k < N_REL * C) val = W1[(size_t)k * C + n];
        else               val = root1[(size_t)(k - N_REL * C) * C + n];
        Bp1[frag_index(k, n)] = __float2bfloat16(val);
    } else if (bid < MV_B + 2 * RP_B) {
        int idx = (bid - MV_B - RP_B) * 256 + threadIdx.x;
        int k = idx >> 7, n = idx & 127;
        const float* row = (k < N_REL * C) ? (W2 + (size_t)k * C)
                                           : (root2 + (size_t)(k - N_REL * C) * C);
        float acc = 0.f;
        for (int m = 0; m < C; m++)
            acc += row[m] * linW[(size_t)m * C + n];
        Bp2[frag_index(k, n)] = __float2bfloat16(acc);
    } else {
        int n = threadIdx.x;
        if (n < 128) {
            float acc = linb[n];
            for (int m = 0; m < C; m++)
                acc += b2[m] * linW[(size_t)m * C + n];
            b2p[n] = acc;
        }
    }
}

// ---------------------------------------------------------------- fused layer
// Block: 16 nodes, 256 threads (4 waves).
// Phase 1: wave w owns local segments [32w, 32w+32) = nodes 4w..4w+3 (contiguous
//          CSR edge range). Edges processed in batches of 8 -> 8 gathers in flight.
// Phase 2: MFMA [16 x KTOT] x [KTOT x 128], 2 N-tiles per wave.
template <int RELU, int OUT_F32>
__global__ __launch_bounds__(256, 4) void fused_layer(
        const unsigned int* __restrict__ featu,  // [N][64] bf16 pairs
        const int*   __restrict__ offs,          // [N_SEG+1]
        const int*   __restrict__ srcs,          // [N_EDGES]
        const short8* __restrict__ Bp,           // fragment-packed bf16 weights
        const float* __restrict__ bias,          // [128] fp32
        void* __restrict__ outp)                 // [N][128] fp32 or bf16
{
    __shared__ __align__(16) unsigned int At[16 * (A_STRIDE / 2)];  // bf16 pairs
    __shared__ int offsL[129];
    const int tid  = threadIdx.x;
    const int lane = tid & 63;
    const int w    = tid >> 6;
    const int v0   = blockIdx.x * 16;

    // block-level CSR offsets -> LDS (global segs [v0*8, v0*8+128])
    if (tid < 129) offsL[tid] = offs[v0 * 8 + tid];

    // zero the 4 pad pairs per row
    if (tid < 16 * 4) At[(tid >> 2) * (A_STRIDE / 2) + 576 + (tid & 3)] = 0u;

    // self rows -> k range [1024..1151]
    for (int q = tid; q < 16 * 64; q += 256) {
        int node = q >> 6, p = q & 63;
        At[node * (A_STRIDE / 2) + 512 + p] = featu[(size_t)(v0 + node) * 64 + p];
    }
    __syncthreads();

    // ---- aggregation over wave-owned contiguous edge range
    {
        const int segLo = w * 32;
        const int segHi = segLo + 32;
        int curSeg = segLo;
        int segEnd = offsL[curSeg + 1];
        int i      = offsL[segLo];
        const int eend = offsL[segHi];
        float a0 = 0.f, a1 = 0.f;

        while (i < eend) {
            int m = eend - i; if (m > 8) m = 8;
            unsigned int vals[8];
#pragma unroll
            for (int j = 0; j < 8; j++) {
                if (j < m) {
                    int sv = srcs[i + j];
                    vals[j] = featu[(size_t)sv * 64 + lane];
                }
            }
#pragma unroll
            for (int j = 0; j < 8; j++) {
                if (j < m) {
                    while (curSeg < segHi && i + j == segEnd) {
                        int b = offsL[curSeg];
                        float inv = (segEnd > b) ? 1.0f / (float)(segEnd - b) : 0.0f;
                        union { bf162 h; unsigned int u; } cv;
                        cv.h = bf162(__float2bfloat16(a0 * inv), __float2bfloat16(a1 * inv));
                        At[(curSeg >> 3) * (A_STRIDE / 2) + (curSeg & 7) * 64 + lane] = cv.u;
                        a0 = 0.f; a1 = 0.f;
                        curSeg++;
                        if (curSeg < segHi) segEnd = offsL[curSeg + 1];
                    }
                    union { bf162 h; unsigned int u; } uv; uv.u = vals[j];
                    a0 += __low2float(uv.h);
                    a1 += __high2float(uv.h);
                }
            }
            i += m;
        }
        // trailing flushes (final segment with edges + empty tails)
        while (curSeg < segHi) {
            int b = offsL[curSeg];
            int e2 = offsL[curSeg + 1];
            float inv = (e2 > b) ? 1.0f / (float)(e2 - b) : 0.0f;
            union { bf162 h; unsigned int u; } cv;
            cv.h = bf162(__float2bfloat16(a0 * inv), __float2bfloat16(a1 * inv));
            At[(curSeg >> 3) * (A_STRIDE / 2) + (curSeg & 7) * 64 + lane] = cv.u;
            a0 = 0.f; a1 = 0.f;
            curSeg++;
        }
    }
    __syncthreads();

    // ---- MFMA GEMM
    const int quad = lane >> 4, n15 = lane & 15;
    const int nt0 = 2 * w, nt1 = 2 * w + 1;
    f32x4 acc0 = {0.f, 0.f, 0.f, 0.f};
    f32x4 acc1 = {0.f, 0.f, 0.f, 0.f};
    const short* Ash = (const short*)At;

    for (int kc = 0; kc < KC_CNT; kc++) {
        short8 a  = *reinterpret_cast<const short8*>(Ash + n15 * A_STRIDE + kc * 32 + quad * 8);
        short8 b0 = Bp[(size_t)(nt0 * KC_CNT + kc) * 64 + lane];
        short8 b1 = Bp[(size_t)(nt1 * KC_CNT + kc) * 64 + lane];
        acc0 = __builtin_amdgcn_mfma_f32_16x16x32_bf16(a, b0, acc0, 0, 0, 0);
        acc1 = __builtin_amdgcn_mfma_f32_16x16x32_bf16(a, b1, acc1, 0, 0, 0);
    }

    // epilogue: D[m = quad*4 + r][n = nt*16 + n15]
#pragma unroll
    for (int t = 0; t < 2; t++) {
        int nt = t ? nt1 : nt0;
        f32x4 acc = t ? acc1 : acc0;
        int col = nt * 16 + n15;
        float bv = bias[col];
#pragma unroll
        for (int r = 0; r < 4; r++) {
            int m = quad * 4 + r;
            float v = acc[r] + bv;
            if (RELU) v = fmaxf(v, 0.f);
            if (OUT_F32) ((float*)outp)[(size_t)(v0 + m) * C + col] = v;
            else         ((bf16*)outp)[(size_t)(v0 + m) * C + col] = __float2bfloat16(v);
        }
    }
}

// ---------------------------------------------------------------- launch
// fp32 I/O. ZERO d_ws usage. Provenance:
//   d_out lo  : CSR build scratch (cnt/offs/partials/srcs)   [until finalize]
//   d_out hi  : x converted to bf16 (12.8 MB @ +8 MB)        [until layer 1 done]
//   ei buffer : final CSR (offs2 + srcs2, 5.6 MB)            [dead after fill]
//   et buffer : packed weights Bp1/Bp2/b2p (0.6 MB)          [dead after fill]
//   x buffer  : h1 bf16 (12.8 MB)                            [x fp32 dead after prep]
//   d_out     : final fp32 output (layer 2 writes directly)
extern "C" void kernel_launch(void* const* d_in, const int* in_sizes, int n_in,
                              void* d_out, int out_size, void* d_ws, size_t ws_size,
                              hipStream_t stream) {
    const float* x     = (const float*)d_in[0];
    const int*   ei    = (const int*)d_in[1];
    const float* W1    = (const float*)d_in[3];
    const float* root1 = (const float*)d_in[4];
    const float* b1    = (const float*)d_in[5];
    const float* W2    = (const float*)d_in[6];
    const float* root2 = (const float*)d_in[7];
    const float* b2    = (const float*)d_in[8];
    const float* linW  = (const float*)d_in[9];
    const float* linb  = (const float*)d_in[10];
    const int* et  = (const int*)d_in[2];
    const int* src = ei;
    const int* dst = ei + N_EDGES;

    // ---- d_out scratch
    char* ob = (char*)d_out;
    int* cnt_i    = (int*)(ob + 0);          // 1,600,000 B (then fill cursor)
    int* offs_t   = (int*)(ob + 1600256);    // 1,600,004 B
    int* partials = (int*)(ob + 3200512);
    int* pofs     = (int*)(ob + 3202176);
    int* srcs_t   = (int*)(ob + 3204096);    // 4,000,000 B -> ends 7,204,096
    unsigned int* xb16 = (unsigned int*)(ob + 8388608);  // 12.8 MB -> ends 21,188,608 < 25.6 MB

    // ---- ei buffer: final CSR
    char* eb = (char*)d_in[1];
    int* offs2 = (int*)(eb + 0);
    int* srcs2 = (int*)(eb + 1600256);       // ends 5,600,256 < 8 MB

    // ---- et buffer: packed weights
    char* tb = (char*)d_in[2];
    bf16*  Bp1 = (bf16*)(tb + 0);
    bf16*  Bp2 = (bf16*)(tb + 295168);
    float* b2p = (float*)(tb + 590336);      // ends < 4 MB

    unsigned int* h1 = (unsigned int*)d_in[0];   // layer-1 bf16 out -> x buffer
    float* out = (float*)d_out;

    const int nscan1 = (N_SEG + 1023) / 1024;    // 391

    hipMemsetAsync(cnt_i, 0, (size_t)N_SEG * 4, stream);
    prep_kernel<<<CVT_BLOCKS + CNT_BLOCKS, 256, 0, stream>>>(
        (const float2*)x, xb16, dst, et, cnt_i);
    scan1_kernel<<<nscan1, 256, 0, stream>>>(cnt_i, offs_t, partials, N_SEG);
    scan2_kernel<<<1, 512, 0, stream>>>(partials, pofs, nscan1);
    scan3_kernel<<<nscan1, 256, 0, stream>>>(offs_t, pofs, cnt_i, N_SEG, N_EDGES);
    fill_kernel<<<(N_EDGES + 255) / 256, 256, 0, stream>>>(src, dst, et, cnt_i, srcs_t);
    finalize_kernel<<<MV_B + 2 * RP_B + 1, 256, 0, stream>>>(
        offs_t, srcs_t, offs2, srcs2, W1, root1, W2, root2, linW, b2, linb,
        Bp1, Bp2, b2p);

    fused_layer<1, 0><<<N_NODES / 16, 256, 0, stream>>>(
        xb16, offs2, srcs2, (const short8*)Bp1, b1, (void*)h1);
    fused_layer<0, 1><<<N_NODES / 16, 256, 0, stream>>>(
        h1, offs2, srcs2, (const short8*)Bp2, b2p, (void*)out);

    (void)in_sizes; (void)n_in; (void)out_size; (void)d_ws; (void)ws_size;
}